// Round 6
// baseline (272.996 us; speedup 1.0000x reference)
//
#include <hip/hip_runtime.h>
#include <hip/hip_bf16.h>
#include <cstdint>

// Problem constants
#define B_    8
#define T_    1024
#define S_    1024
#define E_    1024
#define NH_   16
#define HD_   64
#define KVIN_ 256
#define SCALE_ 0.125f   // HEAD_DIM^-0.5 = 64^-0.5

typedef __attribute__((ext_vector_type(8))) short bf16x8;
typedef __attribute__((ext_vector_type(4))) float f32x4;
typedef unsigned short us;

__device__ __forceinline__ us f2bf(float x) {
  union { float f; unsigned u; } v; v.f = x;
  unsigned r = v.u + 0x7fffu + ((v.u >> 16) & 1u);   // RNE
  return (us)(r >> 16);
}

// round-half-up bf16 (2 VALU ops); valid for non-negative finite values (P = exp >= 0)
__device__ __forceinline__ us f2bf_p(float x) {
  union { float f; unsigned u; } v; v.f = x;
  return (us)((v.u + 0x8000u) >> 16);
}

__device__ __forceinline__ void gl_lds16(const us* g, const us* l) {
  __builtin_amdgcn_global_load_lds(
      (const __attribute__((address_space(1))) void*)g,
      (__attribute__((address_space(3))) void*)l, 16, 0, 0);
}

// ---------------- fused prep: fp32->bf16 converts + 4 weight transpose-converts --------
__device__ __forceinline__ void cvt_body8(const float* __restrict__ in,
                                          us* __restrict__ out, int blk, int tid) {
  #pragma unroll
  for (int j = 0; j < 8; ++j) {
    int i = blk * 2048 + j * 256 + tid;
    float4 v = ((const float4*)in)[i];
    ushort4 o;
    o.x = f2bf(v.x); o.y = f2bf(v.y); o.z = f2bf(v.z); o.w = f2bf(v.w);
    ((ushort4*)out)[i] = o;
  }
}

__device__ __forceinline__ void tr_body(const float* __restrict__ W,
                                        us* __restrict__ Wt,
                                        int K, int N, int bx, int by, int tid) {
  __shared__ float t[32][33];
  int n0 = bx * 32, k0 = by * 32;
  int tx = tid & 31, ty = tid >> 5;   // 32x8
  #pragma unroll
  for (int r = 0; r < 32; r += 8)
    t[ty + r][tx] = W[(size_t)(k0 + ty + r) * N + n0 + tx];
  __syncthreads();
  #pragma unroll
  for (int r = 0; r < 32; r += 8)
    Wt[(size_t)(n0 + ty + r) * K + k0 + tx] = f2bf(t[tx][ty + r]);
}

// block ranges: [0,1024) cvt hs, [1024,1280) cvt kv, then tr Wq(1024), Wk(256), Wv(256), Wo(1024)
__global__ __launch_bounds__(256) void k_prep(const float* __restrict__ hs, us* __restrict__ hsb,
                                              const float* __restrict__ kv, us* __restrict__ kvb,
                                              const float* __restrict__ Wq, us* __restrict__ Wqt,
                                              const float* __restrict__ Wk, us* __restrict__ Wkt,
                                              const float* __restrict__ Wv, us* __restrict__ Wvt,
                                              const float* __restrict__ Wo, us* __restrict__ Wot) {
  const int bid = blockIdx.x, tid = threadIdx.x;
  if (bid < 1024) { cvt_body8(hs, hsb, bid, tid); return; }
  if (bid < 1280) { cvt_body8(kv, kvb, bid - 1024, tid); return; }
  int id = bid - 1280;
  if (id < 1024)      tr_body(Wq, Wqt, 1024, 1024, id & 31, id >> 5, tid);
  else if (id < 1280) tr_body(Wk, Wkt, 256, 1024, (id - 1024) & 31, (id - 1024) >> 5, tid);
  else if (id < 1536) tr_body(Wv, Wvt, 256, 1024, (id - 1280) & 31, (id - 1280) >> 5, tid);
  else                tr_body(Wo, Wot, 1024, 1024, (id - 1536) & 31, (id - 1536) >> 5, tid);
}

// ---------------- bf16 bt-GEMM body (2-PHASE double-buffer, 128x64 tile) ----------------
// R6: T3-minimum 2-phase (m230: 2ph = 92% of 8ph): stage(t+1) issued into the other
// LDS buffer BEFORE compute(t); single __syncthreads per K-step (its implicit vmcnt(0)
// waits on loads that had a full compute phase in flight). LDS 49152 B -> 3 blocks/CU.
// EPI: 1 = K proj (acc+b -> bf16), 2 = V proj (LDS-transposed coalesced write), 3 = fp32
template <int EPI>
__device__ __forceinline__ void gemm_body(const us* __restrict__ A, int lda,
                                          const us* __restrict__ Bt, int ldb,
                                          const float* __restrict__ bias,
                                          void* __restrict__ Cv, int K) {
  __shared__ us smem[24576];   // 49152 B: 2 x {As[128x64] | Bs[64x64]}; EPI2 epi reuses [0,17408)
  const int tid = threadIdx.x, lane = tid & 63, w = tid >> 6;
  const int quad = lane >> 4, lc = lane & 15;
  const int m0 = blockIdx.x * 128, n0 = blockIdx.y * 64;
  const int wm = (w >> 1) * 64, wn = (w & 1) * 32;

  f32x4 acc[4][2] = {};

  const int strow = lane >> 3;
  const int stcol = (((lane & 7) ^ ((lane >> 3) & 7)) * 8);
  const us* Ag = A + (size_t)(m0 + w * 32 + strow) * lda + stcol;
  const us* Bg = Bt + (size_t)(n0 + w * 16 + strow) * ldb + stcol;

  // prologue: stage tile 0 into buffer 0
  #pragma unroll
  for (int r = 0; r < 4; ++r)
    gl_lds16(Ag + (size_t)r * 8 * lda, smem + (w * 4 + r) * 512);
  #pragma unroll
  for (int r = 0; r < 2; ++r)
    gl_lds16(Bg + (size_t)r * 8 * ldb, smem + 8192 + (w * 2 + r) * 512);
  __syncthreads();

  int cur = 0;
  for (int k0 = 0; k0 < K; k0 += 64) {
    us* Sb = smem + cur * 12288;
    // issue NEXT tile's stage into the other buffer — flies under this tile's compute
    if (k0 + 64 < K) {
      us* Nb = smem + (cur ^ 1) * 12288;
      #pragma unroll
      for (int r = 0; r < 4; ++r)
        gl_lds16(Ag + (size_t)r * 8 * lda + k0 + 64, Nb + (w * 4 + r) * 512);
      #pragma unroll
      for (int r = 0; r < 2; ++r)
        gl_lds16(Bg + (size_t)r * 8 * ldb + k0 + 64, Nb + 8192 + (w * 2 + r) * 512);
    }
    #pragma unroll
    for (int ks = 0; ks < 2; ++ks) {
      bf16x8 af[4], bfr[2];
      #pragma unroll
      for (int i = 0; i < 4; ++i)
        af[i]  = *(const bf16x8*)(Sb + (wm + i * 16 + lc) * 64 + (((ks * 4 + quad) ^ (lc & 7)) * 8));
      #pragma unroll
      for (int i = 0; i < 2; ++i)
        bfr[i] = *(const bf16x8*)(Sb + 8192 + (wn + i * 16 + lc) * 64 + (((ks * 4 + quad) ^ (lc & 7)) * 8));
      #pragma unroll
      for (int mt = 0; mt < 4; ++mt)
        #pragma unroll
        for (int nt = 0; nt < 2; ++nt)
          acc[mt][nt] = __builtin_amdgcn_mfma_f32_16x16x32_bf16(af[mt], bfr[nt], acc[mt][nt], 0, 0, 0);
    }
    // single barrier: implicit vmcnt(0) covers next stage (had compute-time in flight);
    // orders all reads of Sb before iteration t+1 overwrites it
    __syncthreads();
    cur ^= 1;
  }

  if constexpr (EPI == 2) {
    #pragma unroll
    for (int nt = 0; nt < 2; ++nt) {
      const float bn = bias[n0 + wn + nt * 16 + lc];
      #pragma unroll
      for (int mt = 0; mt < 4; ++mt)
        #pragma unroll
        for (int r = 0; r < 4; ++r)
          smem[(wn + nt * 16 + lc) * 136 + wm + mt * 16 + quad * 4 + r] =
              f2bf(acc[mt][nt][r] + bn);
    }
    __syncthreads();
    const int nl = tid >> 2, sp = (tid & 3) * 32;
    const int bb = m0 >> 10, sw = m0 & 1023;
    us* dst = (us*)Cv + ((size_t)(bb * 1024) + n0 + nl) * 1024 + sw + sp;
    #pragma unroll
    for (int j = 0; j < 4; ++j) {
      uint4 v = *(const uint4*)(smem + nl * 136 + sp + j * 8);
      *(uint4*)(dst + j * 8) = v;
    }
    return;
  }

  #pragma unroll
  for (int mt = 0; mt < 4; ++mt) {
    #pragma unroll
    for (int nt = 0; nt < 2; ++nt) {
      const int n = n0 + wn + nt * 16 + lc;
      const float bn = bias[n];
      #pragma unroll
      for (int r = 0; r < 4; ++r) {
        const int m = m0 + wm + mt * 16 + quad * 4 + r;
        float v = acc[mt][nt][r] + bn;
        if constexpr (EPI == 1)
          ((us*)Cv)[(size_t)m * E_ + n] = f2bf(v);
        else
          ((float*)Cv)[(size_t)m * E_ + n] = v;
      }
    }
  }
}

// ---------------- 128x128-tile bf16 bt-GEMM, 2-PHASE double-buffer -------------------
// 4 waves 2x2, acc[4][4], 32 MFMA + 16 ds_read_b128 per K-step. LDS 65536 B -> 2 blocks/CU
// (matches the (64,8) grid's 2 blocks/CU — prefetch replaces the missing TLP).
template <int EPI>
__device__ __forceinline__ void gemm128_body(const us* __restrict__ A, int lda,
                                             const us* __restrict__ Bt, int ldb,
                                             const float* __restrict__ bias,
                                             void* __restrict__ Cv, int K) {
  __shared__ us smem[32768];   // 65536 B: 2 x {As[128x64] | Bs[128x64]}
  const int tid = threadIdx.x, lane = tid & 63, w = tid >> 6;
  const int quad = lane >> 4, lc = lane & 15;
  const int m0 = blockIdx.x * 128, n0 = blockIdx.y * 128;
  const int wm = (w >> 1) * 64, wn = (w & 1) * 64;

  f32x4 acc[4][4] = {};

  const int strow = lane >> 3;
  const int stcol = (((lane & 7) ^ ((lane >> 3) & 7)) * 8);
  const us* Ag = A + (size_t)(m0 + w * 32 + strow) * lda + stcol;
  const us* Bg = Bt + (size_t)(n0 + w * 32 + strow) * ldb + stcol;

  // prologue: stage tile 0 into buffer 0
  #pragma unroll
  for (int r = 0; r < 4; ++r) {
    gl_lds16(Ag + (size_t)r * 8 * lda, smem + (w * 4 + r) * 512);
    gl_lds16(Bg + (size_t)r * 8 * ldb, smem + 8192 + (w * 4 + r) * 512);
  }
  __syncthreads();

  int cur = 0;
  for (int k0 = 0; k0 < K; k0 += 64) {
    us* Sb = smem + cur * 16384;
    if (k0 + 64 < K) {
      us* Nb = smem + (cur ^ 1) * 16384;
      #pragma unroll
      for (int r = 0; r < 4; ++r) {
        gl_lds16(Ag + (size_t)r * 8 * lda + k0 + 64, Nb + (w * 4 + r) * 512);
        gl_lds16(Bg + (size_t)r * 8 * ldb + k0 + 64, Nb + 8192 + (w * 4 + r) * 512);
      }
    }
    #pragma unroll
    for (int ks = 0; ks < 2; ++ks) {
      bf16x8 af[4], bf[4];
      #pragma unroll
      for (int i = 0; i < 4; ++i) {
        af[i] = *(const bf16x8*)(Sb + (wm + i * 16 + lc) * 64 + (((ks * 4 + quad) ^ (lc & 7)) * 8));
        bf[i] = *(const bf16x8*)(Sb + 8192 + (wn + i * 16 + lc) * 64 + (((ks * 4 + quad) ^ (lc & 7)) * 8));
      }
      #pragma unroll
      for (int i = 0; i < 4; ++i)
        #pragma unroll
        for (int j = 0; j < 4; ++j)
          acc[i][j] = __builtin_amdgcn_mfma_f32_16x16x32_bf16(af[i], bf[j], acc[i][j], 0, 0, 0);
    }
    __syncthreads();
    cur ^= 1;
  }

  #pragma unroll
  for (int i = 0; i < 4; ++i) {
    #pragma unroll
    for (int j = 0; j < 4; ++j) {
      const int n = n0 + wn + j * 16 + lc;
      const float bn = bias[n];
      #pragma unroll
      for (int r = 0; r < 4; ++r) {
        const int m = m0 + wm + i * 16 + quad * 4 + r;
        float v = acc[i][j][r] + bn;
        if constexpr (EPI == 1)
          ((us*)Cv)[(size_t)m * E_ + n] = f2bf(v);
        else
          ((float*)Cv)[(size_t)m * E_ + n] = v;
      }
    }
  }
}

// K/V projections in one launch: blockIdx.z picks the GEMM. Grid (64, 16, 2).
__global__ __launch_bounds__(256) void k_proj(const us* __restrict__ kvb,
                                              const us* __restrict__ Wkt,
                                              const us* __restrict__ Wvt,
                                              const float* __restrict__ bk,
                                              const float* __restrict__ bv,
                                              us* __restrict__ Kb,
                                              us* __restrict__ Vtb) {
  if (blockIdx.z == 0) gemm_body<1>(kvb, 256, Wkt, 256, bk, (void*)Kb, 256);
  else                 gemm_body<2>(kvb, 256, Wvt, 256, bv, (void*)Vtb, 256);
}

// O-projection on the 128x128 2-phase body. Grid (64, 8).
__global__ __launch_bounds__(256) void k_oproj(const us* __restrict__ Ob,
                                               const us* __restrict__ Wot,
                                               const float* __restrict__ bo,
                                               float* __restrict__ out) {
  gemm128_body<3>(Ob, 1024, Wot, 1024, bo, (void*)out, 1024);
}

// ---------------- flash attention with fused Q-projection (R1 structure) ----------------
// Phase 1: per-block 128x64 Q-tile = hs[b,qt-rows,:] @ Wq[:,h-cols] ((acc+bq)*SCALE, bf16),
// C-layout -> A-layout via the Ps LDS area (same-wave roundtrip, lgkmcnt only).
// Phase 2: T14 async-STAGE reg-prefetch pipeline; mask loads INSIDE the mt-loop directly
// initializing sacc (the MFMA C operand). R2/R3 LESSONS: (a) do NOT hold a 32-float mask
// prefetch across PV (spills at the 64-VGPR heuristic); (b) swapped-QK^T (mfma(K,Q))
// is NET-NEGATIVE (bank conflicts 1.1M->3.2M, 97.6->111.5us) — keep unswapped.
// K/V tile s0+64 global_load'ed to regs UNDER compute of tile s0; raw s_barrier
// (no vmcnt drain) + lgkmcnt(0) publishes the ds_writes. LDS 34816 B -> 4 blocks/CU.
// No online-max (scores O(1)). qt = bidx&7 REQUIRED (XCD pins the mask slice).
__global__ __launch_bounds__(256, 4) void k_attn(const us* __restrict__ hsb,
                                                 const us* __restrict__ Wqt,
                                                 const float* __restrict__ bq,
                                                 const us* __restrict__ Kg_,
                                                 const us* __restrict__ Vt,
                                                 const float* __restrict__ mask,
                                                 const float* __restrict__ lhm,
                                                 us* __restrict__ O) {
  // layout: [0,4096) Ks | [4096,8192) Vs | [8192,17408) Ps[4][32*72]
  // Q-phase reuse: [0,8192) = A-staging (128x64), [8192,12288) = B-staging (64x64)
  __shared__ us smem[17408];
  us* Ks = smem;
  us* Vs = smem + 4096;
  us* Ps = smem + 8192;          // per wave: + w*2304, 32 rows x stride 72

  const int tid = threadIdx.x, lane = tid & 63, w = tid >> 6;
  const int quad = lane >> 4, lc = lane & 15;
  const int bidx = blockIdx.x;
  const int qt = bidx & 7;
  const int h = (bidx >> 3) & 15;
  const int b = bidx >> 7;
  const int q0 = qt * 128 + w * 32;   // this wave's 32 q rows start (within b)

  const int strow = lane >> 3;
  const int stcol = (((lane & 7) ^ ((lane >> 3) & 7)) * 8);

  // phase-2 global sources (per-lane, same addresses the old gl_lds DMA used)
  const us* Kgs = Kg_ + ((size_t)(b * 1024) + w * 16 + strow) * 1024 + h * 64 + stcol;
  const us* Vgs = Vt + ((size_t)((b * 16 + h) * 64) + w * 16 + strow) * 1024 + stcol;

  // ---- Phase 1: Q-tile GEMM (M=128 block rows, N=64 head cols, K=1024) ----
  bf16x8 qf[2][2];
  uint4 kr0, kr1, vr0, vr1;      // phase-2 staging regs
  {
    const us* Ag = hsb + (size_t)(b * 1024 + qt * 128 + w * 32 + strow) * 1024 + stcol;
    const us* Bg = Wqt + (size_t)(h * 64 + w * 16 + strow) * 1024 + stcol;
    f32x4 qacc[2][4] = {};
    for (int k0 = 0; k0 < 1024; k0 += 64) {
      __syncthreads();
      #pragma unroll
      for (int r = 0; r < 4; ++r)
        gl_lds16(Ag + (size_t)r * 8 * 1024 + k0, smem + (w * 4 + r) * 512);
      #pragma unroll
      for (int r = 0; r < 2; ++r)
        gl_lds16(Bg + (size_t)r * 8 * 1024 + k0, smem + 8192 + (w * 2 + r) * 512);
      __syncthreads();
      #pragma unroll
      for (int ks = 0; ks < 2; ++ks) {
        bf16x8 af[2], bfr[4];
        #pragma unroll
        for (int i = 0; i < 2; ++i)
          af[i] = *(const bf16x8*)(smem + (w * 32 + i * 16 + lc) * 64 + (((ks * 4 + quad) ^ (lc & 7)) * 8));
        #pragma unroll
        for (int i = 0; i < 4; ++i)
          bfr[i] = *(const bf16x8*)(smem + 8192 + (i * 16 + lc) * 64 + (((ks * 4 + quad) ^ (lc & 7)) * 8));
        #pragma unroll
        for (int mt = 0; mt < 2; ++mt)
          #pragma unroll
          for (int nt = 0; nt < 4; ++nt)
            qacc[mt][nt] = __builtin_amdgcn_mfma_f32_16x16x32_bf16(af[mt], bfr[nt], qacc[mt][nt], 0, 0, 0);
      }
    }
    // issue phase-2 prologue prefetch (s0 = 0 K/V tile) — latency hides under the
    // Ps epilogue roundtrip + first s-loop barrier; raw barrier below does NOT drain it
    kr0 = *(const uint4*)(Kgs);
    kr1 = *(const uint4*)(Kgs + (size_t)8 * 1024);
    vr0 = *(const uint4*)(Vgs);
    vr1 = *(const uint4*)(Vgs + (size_t)8 * 1024);

    // epilogue: (acc + bq)*SCALE -> bf16 into this wave's Ps area (C-layout rows)
    // raw barrier (not __syncthreads): only guards B-staging reads (already complete
    // via lgkmcnt before the MFMAs) vs Ps overwrite — must not drain the prefetch.
    __builtin_amdgcn_s_barrier();
    #pragma unroll
    for (int nt = 0; nt < 4; ++nt) {
      const float bn = bq[h * 64 + nt * 16 + lc];
      #pragma unroll
      for (int mt = 0; mt < 2; ++mt)
        #pragma unroll
        for (int r = 0; r < 4; ++r)
          Ps[w * 2304 + (mt * 16 + quad * 4 + r) * 72 + nt * 16 + lc] =
              f2bf((qacc[mt][nt][r] + bn) * SCALE_);
    }
    // readback is same-wave (Ps is per-wave) — lgkmcnt suffices, no barrier
    #pragma unroll
    for (int mt = 0; mt < 2; ++mt) {
      qf[mt][0] = *(const bf16x8*)(&Ps[w * 2304 + (mt * 16 + lc) * 72 + quad * 8]);
      qf[mt][1] = *(const bf16x8*)(&Ps[w * 2304 + (mt * 16 + lc) * 72 + 32 + quad * 8]);
    }
  }

  // ---- Phase 2: attention (R12 async-STAGE pipeline) ----
  f32x4 oacc[2][4] = {};
  f32x4 lacc[2] = {};

  bf16x8 ones;
  #pragma unroll
  for (int i = 0; i < 8; ++i) ones[i] = (short)0x3F80;   // bf16 1.0

  const float* mg = mask + ((size_t)(b * 1024 + q0 + quad * 4)) * 1024 + lc;

  for (int s0 = 0; s0 < 1024; s0 += 64) {
    // (1) all waves done READING Ks/Vs from the previous iteration's compute
    __builtin_amdgcn_s_barrier();
    // write staged regs -> LDS (compiler inserts the vmcnt wait for kr/vr here;
    // those loads have had a full compute phase in flight). Contiguous b128
    // per wave (1 KB each) — conflict-free, same layout gl_lds produced.
    *(uint4*)(Ks + (w * 16 + 0) * 64 + lane * 8) = kr0;
    *(uint4*)(Ks + (w * 16 + 8) * 64 + lane * 8) = kr1;
    *(uint4*)(Vs + (w * 16 + 0) * 64 + lane * 8) = vr0;
    *(uint4*)(Vs + (w * 16 + 8) * 64 + lane * 8) = vr1;
    // issue NEXT tile's loads — they fly under this iteration's compute
    if (s0 + 64 < 1024) {
      kr0 = *(const uint4*)(Kgs + (size_t)(s0 + 64) * 1024);
      kr1 = *(const uint4*)(Kgs + (size_t)(s0 + 72) * 1024);
      vr0 = *(const uint4*)(Vgs + (s0 + 64));
      vr1 = *(const uint4*)(Vgs + (size_t)8 * 1024 + (s0 + 64));
    }
    // (2) own ds_writes landed (lgkmcnt counts DS only, not the fresh global loads),
    // then publish cross-wave. "memory" clobber pins the ds_writes/ds_reads ordering.
    asm volatile("s_waitcnt lgkmcnt(0)" ::: "memory");
    __builtin_amdgcn_s_barrier();

    #pragma unroll
    for (int mt = 0; mt < 2; ++mt) {
      // mask values initialize the S accumulator (C operand) — no separate add
      f32x4 sacc[4];
      #pragma unroll
      for (int nt = 0; nt < 4; ++nt)
        #pragma unroll
        for (int r = 0; r < 4; ++r)
          sacc[nt][r] = mg[(size_t)(mt * 16 + r) * 1024 + s0 + nt * 16];

      // S = mask + Q K^T for 16 q-rows x 64 s
      #pragma unroll
      for (int ks = 0; ks < 2; ++ks)
        #pragma unroll
        for (int nt = 0; nt < 4; ++nt) {
          bf16x8 kf = *(const bf16x8*)(Ks + (nt * 16 + lc) * 64 + (((ks * 4 + quad) ^ (lc & 7)) * 8));
          sacc[nt] = __builtin_amdgcn_mfma_f32_16x16x32_bf16(qf[mt][ks], kf, sacc[nt], 0, 0, 0);
        }

      // P = exp(S) -> bf16 LDS (padded stride 72)
      #pragma unroll
      for (int nt = 0; nt < 4; ++nt)
        #pragma unroll
        for (int r = 0; r < 4; ++r) {
          float pv = __expf(sacc[nt][r]);
          Ps[w * 2304 + (mt * 16 + quad * 4 + r) * 72 + nt * 16 + lc] = f2bf_p(pv);
        }
    }

    // O += P V ; l += P . 1   (A = Ps, B = Vs / ones)
    #pragma unroll
    for (int ks = 0; ks < 2; ++ks) {
      bf16x8 pf0 = *(const bf16x8*)(&Ps[w * 2304 + (0  + lc) * 72 + ks * 32 + quad * 8]);
      bf16x8 pf1 = *(const bf16x8*)(&Ps[w * 2304 + (16 + lc) * 72 + ks * 32 + quad * 8]);
      lacc[0] = __builtin_amdgcn_mfma_f32_16x16x32_bf16(pf0, ones, lacc[0], 0, 0, 0);
      lacc[1] = __builtin_amdgcn_mfma_f32_16x16x32_bf16(pf1, ones, lacc[1], 0, 0, 0);
      #pragma unroll
      for (int nt = 0; nt < 4; ++nt) {
        bf16x8 vf = *(const bf16x8*)(Vs + (nt * 16 + lc) * 64 + (((ks * 4 + quad) ^ (lc & 7)) * 8));
        oacc[0][nt] = __builtin_amdgcn_mfma_f32_16x16x32_bf16(pf0, vf, oacc[0][nt], 0, 0, 0);
        oacc[1][nt] = __builtin_amdgcn_mfma_f32_16x16x32_bf16(pf1, vf, oacc[1][nt], 0, 0, 0);
      }
    }
  }

  // epilogue: O = (lhm[h]/l) * oacc -> bf16 [b*1024+t][h*64+d]
  const float hm = lhm[h];
  #pragma unroll
  for (int mt = 0; mt < 2; ++mt) {
    us* Og = O + ((size_t)(b * 1024 + q0 + mt * 16 + quad * 4)) * 1024 + h * 64 + lc;
    #pragma unroll
    for (int r = 0; r < 4; ++r) {
      float inv = hm / lacc[mt][r];
      #pragma unroll
      for (int nt = 0; nt < 4; ++nt)
        Og[(size_t)r * 1024 + nt * 16] = f2bf(oacc[mt][nt][r] * inv);
    }
  }
}

extern "C" void kernel_launch(void* const* d_in, const int* in_sizes, int n_in,
                              void* d_out, int out_size, void* d_ws, size_t ws_size,
                              hipStream_t stream) {
  (void)in_sizes; (void)n_in; (void)out_size; (void)ws_size;
  const float* hs   = (const float*)d_in[0];
  const float* kv   = (const float*)d_in[1];
  const float* mask = (const float*)d_in[2];
  const float* lhm  = (const float*)d_in[3];
  const float* Wq   = (const float*)d_in[4];
  const float* bq   = (const float*)d_in[5];
  const float* Wk   = (const float*)d_in[6];
  const float* bk   = (const float*)d_in[7];
  const float* Wv   = (const float*)d_in[8];
  const float* bv   = (const float*)d_in[9];
  const float* Wo   = (const float*)d_in[10];
  const float* bo   = (const float*)d_in[11];
  float* out = (float*)d_out;

  char* p = (char*)d_ws;
  auto alloc = [&](size_t bytes) { char* r = p; p += (bytes + 255) & ~(size_t)255; return r; };
  us* hsb = (us*)alloc((size_t)B_ * T_ * E_ * 2);        // 16 MB
  us* kvb = (us*)alloc((size_t)B_ * S_ * KVIN_ * 2);     // 4 MB
  us* Wqt = (us*)alloc((size_t)E_ * E_ * 2);             // 2 MB
  us* Wkt = (us*)alloc((size_t)E_ * KVIN_ * 2);          // 0.5 MB
  us* Wvt = (us*)alloc((size_t)E_ * KVIN_ * 2);          // 0.5 MB
  us* Wot = (us*)alloc((size_t)E_ * E_ * 2);             // 2 MB
  us* Kb  = (us*)alloc((size_t)B_ * S_ * E_ * 2);        // 16 MB
  us* Vtb = (us*)alloc((size_t)B_ * S_ * E_ * 2);        // 16 MB
  us* Ob  = (us*)alloc((size_t)B_ * T_ * E_ * 2);        // 16 MB

  // 1. fused conversions + weight transposes (1 launch)
  k_prep<<<3840, 256, 0, stream>>>(hs, hsb, kv, kvb, Wq, Wqt, Wk, Wkt, Wv, Wvt, Wo, Wot);

  // 2. K/V projections (z = 0/1); grid (m-panels, n-panels, z)
  k_proj<<<dim3(64, 16, 2), 256, 0, stream>>>(kvb, Wkt, Wvt, bk, bv, Kb, Vtb);

  // 3. attention with fused Q-projection (qt fast -> XCD pins the shared mask slice)
  k_attn<<<1024, 256, 0, stream>>>(hsb, Wqt, bq, Kb, Vtb, mask, lhm, Ob);

  // 4. output projection -> fp32 (128x128 tile, 2-phase)
  k_oproj<<<dim3(64, 8), 256, 0, stream>>>(Ob, Wot, bo, out);
}

// Round 7
// 246.689 us; speedup vs baseline: 1.1066x; 1.1066x over previous
//
#include <hip/hip_runtime.h>
#include <hip/hip_bf16.h>
#include <cstdint>

// Problem constants
#define B_    8
#define T_    1024
#define S_    1024
#define E_    1024
#define NH_   16
#define HD_   64
#define KVIN_ 256
#define SCALE_ 0.125f   // HEAD_DIM^-0.5 = 64^-0.5

typedef __attribute__((ext_vector_type(8))) short bf16x8;
typedef __attribute__((ext_vector_type(4))) float f32x4;
typedef unsigned short us;

__device__ __forceinline__ us f2bf(float x) {
  union { float f; unsigned u; } v; v.f = x;
  unsigned r = v.u + 0x7fffu + ((v.u >> 16) & 1u);   // RNE
  return (us)(r >> 16);
}

// round-half-up bf16 (2 VALU ops); valid for non-negative finite values (P = exp >= 0)
__device__ __forceinline__ us f2bf_p(float x) {
  union { float f; unsigned u; } v; v.f = x;
  return (us)((v.u + 0x8000u) >> 16);
}

__device__ __forceinline__ void gl_lds16(const us* g, const us* l) {
  __builtin_amdgcn_global_load_lds(
      (const __attribute__((address_space(1))) void*)g,
      (__attribute__((address_space(3))) void*)l, 16, 0, 0);
}

// ---------------- fused prep: fp32->bf16 converts + 4 weight transpose-converts --------
__device__ __forceinline__ void cvt_body8(const float* __restrict__ in,
                                          us* __restrict__ out, int blk, int tid) {
  #pragma unroll
  for (int j = 0; j < 8; ++j) {
    int i = blk * 2048 + j * 256 + tid;
    float4 v = ((const float4*)in)[i];
    ushort4 o;
    o.x = f2bf(v.x); o.y = f2bf(v.y); o.z = f2bf(v.z); o.w = f2bf(v.w);
    ((ushort4*)out)[i] = o;
  }
}

__device__ __forceinline__ void tr_body(const float* __restrict__ W,
                                        us* __restrict__ Wt,
                                        int K, int N, int bx, int by, int tid) {
  __shared__ float t[32][33];
  int n0 = bx * 32, k0 = by * 32;
  int tx = tid & 31, ty = tid >> 5;   // 32x8
  #pragma unroll
  for (int r = 0; r < 32; r += 8)
    t[ty + r][tx] = W[(size_t)(k0 + ty + r) * N + n0 + tx];
  __syncthreads();
  #pragma unroll
  for (int r = 0; r < 32; r += 8)
    Wt[(size_t)(n0 + ty + r) * K + k0 + tx] = f2bf(t[tx][ty + r]);
}

// block ranges: [0,1024) cvt hs, [1024,1280) cvt kv, then tr Wq(1024), Wk(256), Wv(256), Wo(1024)
__global__ __launch_bounds__(256) void k_prep(const float* __restrict__ hs, us* __restrict__ hsb,
                                              const float* __restrict__ kv, us* __restrict__ kvb,
                                              const float* __restrict__ Wq, us* __restrict__ Wqt,
                                              const float* __restrict__ Wk, us* __restrict__ Wkt,
                                              const float* __restrict__ Wv, us* __restrict__ Wvt,
                                              const float* __restrict__ Wo, us* __restrict__ Wot) {
  const int bid = blockIdx.x, tid = threadIdx.x;
  if (bid < 1024) { cvt_body8(hs, hsb, bid, tid); return; }
  if (bid < 1280) { cvt_body8(kv, kvb, bid - 1024, tid); return; }
  int id = bid - 1280;
  if (id < 1024)      tr_body(Wq, Wqt, 1024, 1024, id & 31, id >> 5, tid);
  else if (id < 1280) tr_body(Wk, Wkt, 256, 1024, (id - 1024) & 31, (id - 1024) >> 5, tid);
  else if (id < 1536) tr_body(Wv, Wvt, 256, 1024, (id - 1280) & 31, (id - 1280) >> 5, tid);
  else                tr_body(Wo, Wot, 1024, 1024, (id - 1536) & 31, (id - 1536) >> 5, tid);
}

// ---------------- bf16 bt-GEMM body (single-buffer, 128x64 tile) ----------------
// R7: REVERTED to the R0/R1 measured-best form. R5's 128x128 tile (2 blocks/CU) and
// R6's 2-phase dbuf (LDS 48/64 KB, lower occupancy) were both neutral-to-negative on
// the total (non-attn 152 -> 165 -> 175 us). This 24 KB single-buffer + (64,16) grid
// configuration produced the best measured totals; do not touch again.
// EPI: 1 = K proj (acc+b -> bf16), 2 = V proj (LDS-transposed coalesced write), 3 = fp32
template <int EPI>
__device__ __forceinline__ void gemm_body(const us* __restrict__ A, int lda,
                                          const us* __restrict__ Bt, int ldb,
                                          const float* __restrict__ bias,
                                          void* __restrict__ Cv, int K) {
  __shared__ us smem[12288];   // 24576 B; EPI==2 reuses as Cs[64][136]
  us* As = smem;
  us* Bs = smem + 128 * 64;
  const int tid = threadIdx.x, lane = tid & 63, w = tid >> 6;
  const int quad = lane >> 4, lc = lane & 15;
  const int m0 = blockIdx.x * 128, n0 = blockIdx.y * 64;
  const int wm = (w >> 1) * 64, wn = (w & 1) * 32;

  f32x4 acc[4][2] = {};

  const int strow = lane >> 3;
  const int stcol = (((lane & 7) ^ ((lane >> 3) & 7)) * 8);
  const us* Ag = A + (size_t)(m0 + w * 32 + strow) * lda + stcol;
  const us* Bg = Bt + (size_t)(n0 + w * 16 + strow) * ldb + stcol;

  for (int k0 = 0; k0 < K; k0 += 64) {
    __syncthreads();
    #pragma unroll
    for (int r = 0; r < 4; ++r)
      gl_lds16(Ag + (size_t)r * 8 * lda + k0, As + (w * 4 + r) * 512);
    #pragma unroll
    for (int r = 0; r < 2; ++r)
      gl_lds16(Bg + (size_t)r * 8 * ldb + k0, Bs + (w * 2 + r) * 512);
    __syncthreads();
    #pragma unroll
    for (int ks = 0; ks < 2; ++ks) {
      bf16x8 af[4], bfr[2];
      #pragma unroll
      for (int i = 0; i < 4; ++i)
        af[i]  = *(const bf16x8*)(As + (wm + i * 16 + lc) * 64 + (((ks * 4 + quad) ^ (lc & 7)) * 8));
      #pragma unroll
      for (int i = 0; i < 2; ++i)
        bfr[i] = *(const bf16x8*)(Bs + (wn + i * 16 + lc) * 64 + (((ks * 4 + quad) ^ (lc & 7)) * 8));
      #pragma unroll
      for (int mt = 0; mt < 4; ++mt)
        #pragma unroll
        for (int nt = 0; nt < 2; ++nt)
          acc[mt][nt] = __builtin_amdgcn_mfma_f32_16x16x32_bf16(af[mt], bfr[nt], acc[mt][nt], 0, 0, 0);
    }
  }

  if constexpr (EPI == 2) {
    __syncthreads();
    #pragma unroll
    for (int nt = 0; nt < 2; ++nt) {
      const float bn = bias[n0 + wn + nt * 16 + lc];
      #pragma unroll
      for (int mt = 0; mt < 4; ++mt)
        #pragma unroll
        for (int r = 0; r < 4; ++r)
          smem[(wn + nt * 16 + lc) * 136 + wm + mt * 16 + quad * 4 + r] =
              f2bf(acc[mt][nt][r] + bn);
    }
    __syncthreads();
    const int nl = tid >> 2, sp = (tid & 3) * 32;
    const int bb = m0 >> 10, sw = m0 & 1023;
    us* dst = (us*)Cv + ((size_t)(bb * 1024) + n0 + nl) * 1024 + sw + sp;
    #pragma unroll
    for (int j = 0; j < 4; ++j) {
      uint4 v = *(const uint4*)(smem + nl * 136 + sp + j * 8);
      *(uint4*)(dst + j * 8) = v;
    }
    return;
  }

  #pragma unroll
  for (int mt = 0; mt < 4; ++mt) {
    #pragma unroll
    for (int nt = 0; nt < 2; ++nt) {
      const int n = n0 + wn + nt * 16 + lc;
      const float bn = bias[n];
      #pragma unroll
      for (int r = 0; r < 4; ++r) {
        const int m = m0 + wm + mt * 16 + quad * 4 + r;
        float v = acc[mt][nt][r] + bn;
        if constexpr (EPI == 1)
          ((us*)Cv)[(size_t)m * E_ + n] = f2bf(v);
        else
          ((float*)Cv)[(size_t)m * E_ + n] = v;
      }
    }
  }
}

// K/V projections in one launch: blockIdx.z picks the GEMM. Grid (64, 16, 2).
__global__ __launch_bounds__(256) void k_proj(const us* __restrict__ kvb,
                                              const us* __restrict__ Wkt,
                                              const us* __restrict__ Wvt,
                                              const float* __restrict__ bk,
                                              const float* __restrict__ bv,
                                              us* __restrict__ Kb,
                                              us* __restrict__ Vtb) {
  if (blockIdx.z == 0) gemm_body<1>(kvb, 256, Wkt, 256, bk, (void*)Kb, 256);
  else                 gemm_body<2>(kvb, 256, Wvt, 256, bv, (void*)Vtb, 256);
}

__global__ __launch_bounds__(256) void k_oproj(const us* __restrict__ Ob,
                                               const us* __restrict__ Wot,
                                               const float* __restrict__ bo,
                                               float* __restrict__ out) {
  gemm_body<3>(Ob, 1024, Wot, 1024, bo, (void*)out, 1024);
}

// ---------------- flash attention with fused Q-projection ----------------
// Phase 1: per-block 128x64 Q-tile = hs[b,qt-rows,:] @ Wq[:,h-cols] ((acc+bq)*SCALE, bf16),
// C-layout -> A-layout via the Ps LDS area (same-wave roundtrip, lgkmcnt only).
// Phase 2: T14 async-STAGE reg-prefetch pipeline; mask loads INSIDE the mt-loop directly
// initializing sacc. R2/R3 LESSONS: no held mask prefetch (spills); no swapped QK^T
// (bank conflicts 3x). R7 CHANGES:
//  (a) XCD mapping b = bidx&7 (was qt): blocks sharing (b,qt) [mask,hs] AND blocks
//      sharing (b,h) [K/V] are now both co-XCD -> K/V fetched ~1x instead of 8x
//      (FETCH predicted 164 -> ~80-100 MB) and K/V prefetch becomes L2/L3-near.
//      Earlier "(b,h) pinning" failure (FETCH 251 MB) was h-pinning exploding the
//      mask; b-pinning dedups BOTH mask and K/V (B_ == 8 == NXCD).
//  (b) T5 s_setprio(1/0) around phase-2 MFMA clusters only (m191: +4-7% attn with
//      independent blocks per CU at different phases; phase-1 GEMM left alone, m190).
// K/V tile s0+64 global_load'ed to regs UNDER compute of tile s0; raw s_barrier
// (no vmcnt drain) + lgkmcnt(0) publishes the ds_writes. LDS 34816 B -> 4 blocks/CU.
// No online-max (scores O(1)).
__global__ __launch_bounds__(256, 4) void k_attn(const us* __restrict__ hsb,
                                                 const us* __restrict__ Wqt,
                                                 const float* __restrict__ bq,
                                                 const us* __restrict__ Kg_,
                                                 const us* __restrict__ Vt,
                                                 const float* __restrict__ mask,
                                                 const float* __restrict__ lhm,
                                                 us* __restrict__ O) {
  // layout: [0,4096) Ks | [4096,8192) Vs | [8192,17408) Ps[4][32*72]
  // Q-phase reuse: [0,8192) = A-staging (128x64), [8192,12288) = B-staging (64x64)
  __shared__ us smem[17408];
  us* Ks = smem;
  us* Vs = smem + 4096;
  us* Ps = smem + 8192;          // per wave: + w*2304, 32 rows x stride 72

  const int tid = threadIdx.x, lane = tid & 63, w = tid >> 6;
  const int quad = lane >> 4, lc = lane & 15;
  const int bidx = blockIdx.x;
  const int b = bidx & 7;            // XCD = b: dedups mask, hs AND K/V per XCD
  const int h = (bidx >> 3) & 15;
  const int qt = bidx >> 7;
  const int q0 = qt * 128 + w * 32;  // this wave's 32 q rows start (within b)

  const int strow = lane >> 3;
  const int stcol = (((lane & 7) ^ ((lane >> 3) & 7)) * 8);

  // phase-2 global sources (per-lane, same addresses the old gl_lds DMA used)
  const us* Kgs = Kg_ + ((size_t)(b * 1024) + w * 16 + strow) * 1024 + h * 64 + stcol;
  const us* Vgs = Vt + ((size_t)((b * 16 + h) * 64) + w * 16 + strow) * 1024 + stcol;

  // ---- Phase 1: Q-tile GEMM (M=128 block rows, N=64 head cols, K=1024) ----
  bf16x8 qf[2][2];
  uint4 kr0, kr1, vr0, vr1;      // phase-2 staging regs
  {
    const us* Ag = hsb + (size_t)(b * 1024 + qt * 128 + w * 32 + strow) * 1024 + stcol;
    const us* Bg = Wqt + (size_t)(h * 64 + w * 16 + strow) * 1024 + stcol;
    f32x4 qacc[2][4] = {};
    for (int k0 = 0; k0 < 1024; k0 += 64) {
      __syncthreads();
      #pragma unroll
      for (int r = 0; r < 4; ++r)
        gl_lds16(Ag + (size_t)r * 8 * 1024 + k0, smem + (w * 4 + r) * 512);
      #pragma unroll
      for (int r = 0; r < 2; ++r)
        gl_lds16(Bg + (size_t)r * 8 * 1024 + k0, smem + 8192 + (w * 2 + r) * 512);
      __syncthreads();
      #pragma unroll
      for (int ks = 0; ks < 2; ++ks) {
        bf16x8 af[2], bfr[4];
        #pragma unroll
        for (int i = 0; i < 2; ++i)
          af[i] = *(const bf16x8*)(smem + (w * 32 + i * 16 + lc) * 64 + (((ks * 4 + quad) ^ (lc & 7)) * 8));
        #pragma unroll
        for (int i = 0; i < 4; ++i)
          bfr[i] = *(const bf16x8*)(smem + 8192 + (i * 16 + lc) * 64 + (((ks * 4 + quad) ^ (lc & 7)) * 8));
        #pragma unroll
        for (int mt = 0; mt < 2; ++mt)
          #pragma unroll
          for (int nt = 0; nt < 4; ++nt)
            qacc[mt][nt] = __builtin_amdgcn_mfma_f32_16x16x32_bf16(af[mt], bfr[nt], qacc[mt][nt], 0, 0, 0);
      }
    }
    // issue phase-2 prologue prefetch (s0 = 0 K/V tile) — latency hides under the
    // Ps epilogue roundtrip + first s-loop barrier; raw barrier below does NOT drain it
    kr0 = *(const uint4*)(Kgs);
    kr1 = *(const uint4*)(Kgs + (size_t)8 * 1024);
    vr0 = *(const uint4*)(Vgs);
    vr1 = *(const uint4*)(Vgs + (size_t)8 * 1024);

    // epilogue: (acc + bq)*SCALE -> bf16 into this wave's Ps area (C-layout rows)
    // raw barrier (not __syncthreads): only guards B-staging reads (already complete
    // via lgkmcnt before the MFMAs) vs Ps overwrite — must not drain the prefetch.
    __builtin_amdgcn_s_barrier();
    #pragma unroll
    for (int nt = 0; nt < 4; ++nt) {
      const float bn = bq[h * 64 + nt * 16 + lc];
      #pragma unroll
      for (int mt = 0; mt < 2; ++mt)
        #pragma unroll
        for (int r = 0; r < 4; ++r)
          Ps[w * 2304 + (mt * 16 + quad * 4 + r) * 72 + nt * 16 + lc] =
              f2bf((qacc[mt][nt][r] + bn) * SCALE_);
    }
    // readback is same-wave (Ps is per-wave) — lgkmcnt suffices, no barrier
    #pragma unroll
    for (int mt = 0; mt < 2; ++mt) {
      qf[mt][0] = *(const bf16x8*)(&Ps[w * 2304 + (mt * 16 + lc) * 72 + quad * 8]);
      qf[mt][1] = *(const bf16x8*)(&Ps[w * 2304 + (mt * 16 + lc) * 72 + 32 + quad * 8]);
    }
  }

  // ---- Phase 2: attention (async-STAGE pipeline + setprio) ----
  f32x4 oacc[2][4] = {};
  f32x4 lacc[2] = {};

  bf16x8 ones;
  #pragma unroll
  for (int i = 0; i < 8; ++i) ones[i] = (short)0x3F80;   // bf16 1.0

  const float* mg = mask + ((size_t)(b * 1024 + q0 + quad * 4)) * 1024 + lc;

  for (int s0 = 0; s0 < 1024; s0 += 64) {
    // (1) all waves done READING Ks/Vs from the previous iteration's compute
    __builtin_amdgcn_s_barrier();
    // write staged regs -> LDS (compiler inserts the vmcnt wait for kr/vr here;
    // those loads have had a full compute phase in flight). Contiguous b128
    // per wave (1 KB each) — conflict-free, same layout gl_lds produced.
    *(uint4*)(Ks + (w * 16 + 0) * 64 + lane * 8) = kr0;
    *(uint4*)(Ks + (w * 16 + 8) * 64 + lane * 8) = kr1;
    *(uint4*)(Vs + (w * 16 + 0) * 64 + lane * 8) = vr0;
    *(uint4*)(Vs + (w * 16 + 8) * 64 + lane * 8) = vr1;
    // issue NEXT tile's loads — they fly under this iteration's compute
    if (s0 + 64 < 1024) {
      kr0 = *(const uint4*)(Kgs + (size_t)(s0 + 64) * 1024);
      kr1 = *(const uint4*)(Kgs + (size_t)(s0 + 72) * 1024);
      vr0 = *(const uint4*)(Vgs + (s0 + 64));
      vr1 = *(const uint4*)(Vgs + (size_t)8 * 1024 + (s0 + 64));
    }
    // (2) own ds_writes landed (lgkmcnt counts DS only, not the fresh global loads),
    // then publish cross-wave. "memory" clobber pins the ds_writes/ds_reads ordering.
    asm volatile("s_waitcnt lgkmcnt(0)" ::: "memory");
    __builtin_amdgcn_s_barrier();

    #pragma unroll
    for (int mt = 0; mt < 2; ++mt) {
      // mask values initialize the S accumulator (C operand) — no separate add
      f32x4 sacc[4];
      #pragma unroll
      for (int nt = 0; nt < 4; ++nt)
        #pragma unroll
        for (int r = 0; r < 4; ++r)
          sacc[nt][r] = mg[(size_t)(mt * 16 + r) * 1024 + s0 + nt * 16];

      // S = mask + Q K^T for 16 q-rows x 64 s  (T5: favor this wave while others load)
      __builtin_amdgcn_s_setprio(1);
      #pragma unroll
      for (int ks = 0; ks < 2; ++ks)
        #pragma unroll
        for (int nt = 0; nt < 4; ++nt) {
          bf16x8 kf = *(const bf16x8*)(Ks + (nt * 16 + lc) * 64 + (((ks * 4 + quad) ^ (lc & 7)) * 8));
          sacc[nt] = __builtin_amdgcn_mfma_f32_16x16x32_bf16(qf[mt][ks], kf, sacc[nt], 0, 0, 0);
        }
      __builtin_amdgcn_s_setprio(0);

      // P = exp(S) -> bf16 LDS (padded stride 72)
      #pragma unroll
      for (int nt = 0; nt < 4; ++nt)
        #pragma unroll
        for (int r = 0; r < 4; ++r) {
          float pv = __expf(sacc[nt][r]);
          Ps[w * 2304 + (mt * 16 + quad * 4 + r) * 72 + nt * 16 + lc] = f2bf_p(pv);
        }
    }

    // O += P V ; l += P . 1   (A = Ps, B = Vs / ones)
    __builtin_amdgcn_s_setprio(1);
    #pragma unroll
    for (int ks = 0; ks < 2; ++ks) {
      bf16x8 pf0 = *(const bf16x8*)(&Ps[w * 2304 + (0  + lc) * 72 + ks * 32 + quad * 8]);
      bf16x8 pf1 = *(const bf16x8*)(&Ps[w * 2304 + (16 + lc) * 72 + ks * 32 + quad * 8]);
      lacc[0] = __builtin_amdgcn_mfma_f32_16x16x32_bf16(pf0, ones, lacc[0], 0, 0, 0);
      lacc[1] = __builtin_amdgcn_mfma_f32_16x16x32_bf16(pf1, ones, lacc[1], 0, 0, 0);
      #pragma unroll
      for (int nt = 0; nt < 4; ++nt) {
        bf16x8 vf = *(const bf16x8*)(Vs + (nt * 16 + lc) * 64 + (((ks * 4 + quad) ^ (lc & 7)) * 8));
        oacc[0][nt] = __builtin_amdgcn_mfma_f32_16x16x32_bf16(pf0, vf, oacc[0][nt], 0, 0, 0);
        oacc[1][nt] = __builtin_amdgcn_mfma_f32_16x16x32_bf16(pf1, vf, oacc[1][nt], 0, 0, 0);
      }
    }
    __builtin_amdgcn_s_setprio(0);
  }

  // epilogue: O = (lhm[h]/l) * oacc -> bf16 [b*1024+t][h*64+d]
  const float hm = lhm[h];
  #pragma unroll
  for (int mt = 0; mt < 2; ++mt) {
    us* Og = O + ((size_t)(b * 1024 + q0 + mt * 16 + quad * 4)) * 1024 + h * 64 + lc;
    #pragma unroll
    for (int r = 0; r < 4; ++r) {
      float inv = hm / lacc[mt][r];
      #pragma unroll
      for (int nt = 0; nt < 4; ++nt)
        Og[(size_t)r * 1024 + nt * 16] = f2bf(oacc[mt][nt][r] * inv);
    }
  }
}

extern "C" void kernel_launch(void* const* d_in, const int* in_sizes, int n_in,
                              void* d_out, int out_size, void* d_ws, size_t ws_size,
                              hipStream_t stream) {
  (void)in_sizes; (void)n_in; (void)out_size; (void)ws_size;
  const float* hs   = (const float*)d_in[0];
  const float* kv   = (const float*)d_in[1];
  const float* mask = (const float*)d_in[2];
  const float* lhm  = (const float*)d_in[3];
  const float* Wq   = (const float*)d_in[4];
  const float* bq   = (const float*)d_in[5];
  const float* Wk   = (const float*)d_in[6];
  const float* bk   = (const float*)d_in[7];
  const float* Wv   = (const float*)d_in[8];
  const float* bv   = (const float*)d_in[9];
  const float* Wo   = (const float*)d_in[10];
  const float* bo   = (const float*)d_in[11];
  float* out = (float*)d_out;

  char* p = (char*)d_ws;
  auto alloc = [&](size_t bytes) { char* r = p; p += (bytes + 255) & ~(size_t)255; return r; };
  us* hsb = (us*)alloc((size_t)B_ * T_ * E_ * 2);        // 16 MB
  us* kvb = (us*)alloc((size_t)B_ * S_ * KVIN_ * 2);     // 4 MB
  us* Wqt = (us*)alloc((size_t)E_ * E_ * 2);             // 2 MB
  us* Wkt = (us*)alloc((size_t)E_ * KVIN_ * 2);          // 0.5 MB
  us* Wvt = (us*)alloc((size_t)E_ * KVIN_ * 2);          // 0.5 MB
  us* Wot = (us*)alloc((size_t)E_ * E_ * 2);             // 2 MB
  us* Kb  = (us*)alloc((size_t)B_ * S_ * E_ * 2);        // 16 MB
  us* Vtb = (us*)alloc((size_t)B_ * S_ * E_ * 2);        // 16 MB
  us* Ob  = (us*)alloc((size_t)B_ * T_ * E_ * 2);        // 16 MB

  // 1. fused conversions + weight transposes (1 launch)
  k_prep<<<3840, 256, 0, stream>>>(hs, hsb, kv, kvb, Wq, Wqt, Wk, Wkt, Wv, Wvt, Wo, Wot);

  // 2. K/V projections (z = 0/1); grid (m-panels, n-panels, z)
  k_proj<<<dim3(64, 16, 2), 256, 0, stream>>>(kvb, Wkt, Wvt, bk, bv, Kb, Vtb);

  // 3. attention with fused Q-projection (b fast -> XCD = batch dedups mask+hs+K/V)
  k_attn<<<1024, 256, 0, stream>>>(hsb, Wqt, bq, Kb, Vtb, mask, lhm, Ob);

  // 4. output projection -> fp32
  k_oproj<<<dim3(64, 16), 256, 0, stream>>>(Ob, Wot, bo, out);
}